// Round 10
// baseline (67.979 us; speedup 1.0000x reference)
//
#include <hip/hip_runtime.h>
#include <math.h>

#define LSEQ 4096
#define CIN  256
#define HID  128
#define O3   384
#define NSP  4
#define JTPS (64 / NSP)   // j-tiles per split

typedef float f32x4 __attribute__((ext_vector_type(4)));
typedef short s16x8 __attribute__((ext_vector_type(8)));

typedef const __attribute__((address_space(1))) char* gp_t;
typedef __attribute__((address_space(3))) char* lp_t;

__device__ __forceinline__ short f2bf(float f) {
    union { float f; unsigned u; } c; c.f = f;
    unsigned r = (c.u + 0x7FFFu + ((c.u >> 16) & 1u)) >> 16;
    return (short)r;
}

__device__ __forceinline__ float bf2f(short s) {
    union { unsigned u; float f; } c;
    c.u = ((unsigned)(unsigned short)s) << 16;
    return c.f;
}

__device__ __forceinline__ unsigned cvt_pk_bf16(float lo, float hi) {
    unsigned r;
    asm("v_cvt_pk_bf16_f32 %0, %1, %2" : "=v"(r) : "v"(lo), "v"(hi));
    return r;
}

__device__ __forceinline__ float exp2_hw(float x) {
    float r;
    asm("v_exp_f32 %0, %1" : "=v"(r) : "v"(x));
    return r;
}

__device__ __forceinline__ float bfbits(unsigned v, int hi) {
    union { unsigned u; float f; } c;
    c.u = hi ? (v & 0xffff0000u) : (v << 16);
    return c.f;
}

// ---- pack_xw: x -> xP (B-fragment image), w_qkv -> wP, w_out -> wP2; zero ss ----
__global__ __launch_bounds__(256) void pack_xw(const float* __restrict__ x,
                                               const float* __restrict__ wq,
                                               const float* __restrict__ wo,
                                               short* __restrict__ xP,
                                               short* __restrict__ wP,
                                               short* __restrict__ wP2,
                                               float* __restrict__ ss) {
    const int tid = threadIdx.x;
    if (blockIdx.x >= 1024) {
        if (blockIdx.x == 1024) { ss[tid] = 0.f; ss[256 + tid] = 0.f; }
        const int gid = (blockIdx.x - 1024) * 256 + tid;
        s16x8 o;
        if (gid < 12288) {
            const int m = gid & 15, g = (gid >> 4) & 3, ct = (gid >> 6) & 7;
            const int ot = gid >> 9;
            const float* src = wq + (ot * 16 + m) * 256 + ct * 32 + g * 8;
#pragma unroll
            for (int e = 0; e < 8; ++e) o[e] = f2bf(src[e]);
            *(s16x8*)(wP + (size_t)gid * 8) = o;
        } else {
            const int g2 = gid - 12288;  // 0..4095
            const int m = g2 & 15, g = (g2 >> 4) & 3, ct = (g2 >> 6) & 3;
            const int ot = g2 >> 8;
            const float* src = wo + (ot * 16 + m) * 128 + ct * 32 + g * 8;
#pragma unroll
            for (int e = 0; e < 8; ++e) o[e] = f2bf(src[e]);
            *(s16x8*)(wP2 + (size_t)g2 * 8) = o;
        }
        return;
    }
    __shared__ float tile[32][68];
    const int b = blockIdx.x >> 9, ct = (blockIdx.x >> 6) & 7, lt = blockIdx.x & 63;
    const int c = tid >> 3, l8 = (tid & 7) * 8;
    const float* xb = x + ((size_t)b * CIN + ct * 32 + c) * LSEQ + lt * 64 + l8;
    *(float4*)&tile[c][l8]     = *(const float4*)xb;
    *(float4*)&tile[c][l8 + 4] = *(const float4*)(xb + 4);
    __syncthreads();
    const int g = tid >> 6, l = tid & 63;
    s16x8 o;
#pragma unroll
    for (int e = 0; e < 8; ++e) o[e] = f2bf(tile[g * 8 + e][l]);
    *(s16x8*)(xP + ((size_t)((b * 8 + ct) * 4 + g) * LSEQ + lt * 64 + l) * 8) = o;
}

// ---- mfma_qkv: qkv(bf16)[b][o][l] = sum_c W[o][c] X[c][l]; fused row sum-of-squares ----
__global__ __launch_bounds__(256) void mfma_qkv(const short* __restrict__ xP,
                                                const short* __restrict__ wP,
                                                short* __restrict__ qkv,
                                                float* __restrict__ ss) {
    const int i = blockIdx.x;
    const int slice = i & 31, ot = i >> 5;
    const int b = slice >> 4, lq = slice & 15;
    const int tid = threadIdx.x, lane = tid & 63, w = tid >> 6;
    const int m = lane & 15, g = lane >> 4;
    const int l0 = lq * 256 + w * 64;

    s16x8 wA[8];
#pragma unroll
    for (int ct = 0; ct < 8; ++ct)
        wA[ct] = *(const s16x8*)(wP + ((size_t)((ot * 8 + ct) * 4 + g) * 16 + m) * 8);

    f32x4 acc[4];
#pragma unroll
    for (int t = 0; t < 4; ++t) acc[t] = (f32x4){0.f, 0.f, 0.f, 0.f};

#pragma unroll
    for (int ct = 0; ct < 8; ++ct) {
        const size_t bb = (size_t)((b * 8 + ct) * 4 + g) * LSEQ;
#pragma unroll
        for (int t = 0; t < 4; ++t) {
            const s16x8 xf = *(const s16x8*)(xP + (bb + l0 + t * 16 + m) * 8);
            acc[t] = __builtin_amdgcn_mfma_f32_16x16x32_bf16(wA[ct], xf, acc[t], 0, 0, 0);
        }
    }
    short* qb = qkv + ((size_t)b * O3 + ot * 16) * LSEQ;
#pragma unroll
    for (int t = 0; t < 4; ++t)
#pragma unroll
        for (int r = 0; r < 4; ++r)
            qb[(size_t)(4 * g + r) * LSEQ + l0 + t * 16 + m] = f2bf(acc[t][r]);

    if (ot < 16) {  // q,k rows need the norm
        float s4[4];
#pragma unroll
        for (int r = 0; r < 4; ++r) {
            float s = acc[0][r] * acc[0][r];
#pragma unroll
            for (int t = 1; t < 4; ++t) s = fmaf(acc[t][r], acc[t][r], s);
#pragma unroll
            for (int mk = 1; mk < 16; mk <<= 1) s += __shfl_xor(s, mk);
            s4[r] = s;
        }
        if (m == 0) {
#pragma unroll
            for (int r = 0; r < 4; ++r)
                atomicAdd(ss + b * 256 + ot * 16 + 4 * g + r, s4[r]);
        }
    }
}

// ---- k_pack: qkv bf16 -> qT/kP/vP (scales from ss applied to q,k) ----
// vP fragment-image: group idx t=(pp*4+g)*32+dd -> {V[dd][pp*32+(e>>2)*16+g*4+(e&3)]}
__global__ __launch_bounds__(256) void k_pack(const short* __restrict__ qkv,
                                              const float* __restrict__ ss,
                                              short* __restrict__ qT,
                                              short* __restrict__ kP,
                                              short* __restrict__ vP) {
    __shared__ float tile[32][68];
    const int tid = threadIdx.x;
    const int bh = blockIdx.x & 7, ch = blockIdx.x >> 3;
    const int b = bh >> 2, h = bh & 3;
    const int l0 = ch * 64;
    const short* qg = qkv + ((size_t)b * O3 + h * 32) * LSEQ;
    const short* kg = qg + (size_t)HID * LSEQ;
    const short* vg = qg + (size_t)2 * HID * LSEQ;
    const size_t bho = (size_t)bh * (LSEQ * 32);
    const int d = tid >> 3, c8 = (tid & 7) * 8;

    // ---- Q: transpose + scale -> qT[i][d] ----
    {
        const s16x8 qv = *(const s16x8*)(qg + (size_t)d * LSEQ + l0 + c8);
#pragma unroll
        for (int e = 0; e < 8; ++e) tile[d][c8 + e] = bf2f(qv[e]);
    }
    __syncthreads();
    {
        const int i = tid >> 2, dseg = (tid & 3) * 8;
        s16x8 o;
#pragma unroll
        for (int e = 0; e < 8; ++e) {
            const float sc = 14.4269504088896340736f /
                             fmaxf(sqrtf(ss[b * 256 + h * 32 + dseg + e]), 1e-12f);
            o[e] = f2bf(tile[dseg + e][i] * sc);
        }
        *(s16x8*)(qT + bho + (size_t)(l0 + i) * 32 + dseg) = o;
    }
    __syncthreads();
    // ---- K ----
    {
        const s16x8 kv = *(const s16x8*)(kg + (size_t)d * LSEQ + l0 + c8);
#pragma unroll
        for (int e = 0; e < 8; ++e) tile[d][c8 + e] = bf2f(kv[e]);
    }
    __syncthreads();
    {
        const int gg = tid >> 6, jl = tid & 63;
        s16x8 o;
#pragma unroll
        for (int e = 0; e < 8; ++e) {
            const float sc = 1.0f /
                             fmaxf(sqrtf(ss[b * 256 + 128 + h * 32 + gg * 8 + e]), 1e-12f);
            o[e] = f2bf(tile[gg * 8 + e][jl] * sc);
        }
        *(s16x8*)(kP + bho + (size_t)ch * 2048 + gg * 512 + jl * 8) = o;
    }
    __syncthreads();
    // ---- V (unscaled), PV-fragment image ----
    {
        const s16x8 vv = *(const s16x8*)(vg + (size_t)d * LSEQ + l0 + c8);
#pragma unroll
        for (int e = 0; e < 8; ++e) tile[d][c8 + e] = bf2f(vv[e]);
    }
    __syncthreads();
    {
        const int pp = tid >> 7, g = (tid >> 5) & 3, dd = tid & 31;
        s16x8 o;
#pragma unroll
        for (int e = 0; e < 8; ++e)
            o[e] = f2bf(tile[dd][pp * 32 + ((e >> 2) * 16) + g * 4 + (e & 3)]);
        *(s16x8*)(vP + bho + (size_t)ch * 2048 + tid * 8) = o;
    }
}

// ---- k_attn: MFMA flash attention, split-K=4, exp2 softmax, bf16 partials ----
__global__ __launch_bounds__(512, 8) void k_attn(const short* __restrict__ qT,
                                                 const short* __restrict__ kP,
                                                 const short* __restrict__ vP,
                                                 unsigned* __restrict__ pacc2,
                                                 float* __restrict__ plsum) {
    __shared__ float4 lds_v[1024];   // 16 KB: 2 buffers x (K 4KB | V 4KB)
    char* lds = (char*)lds_v;
    const int tid = threadIdx.x;
    const int lane = tid & 63, w = tid >> 6;
    const int m = lane & 15, g = lane >> 4;
    const int bh = blockIdx.x & 7;           // XCD-friendly
    const int rest = blockIdx.x >> 3;        // 0..127
    const int iblk = rest & 31, sp = rest >> 5;
    const size_t bho = (size_t)bh * (LSEQ * 32);
    const int i0 = iblk * 128 + w * 16;

    const s16x8 qf = *(const s16x8*)(qT + bho + (size_t)(i0 + m) * 32 + g * 8);
    const char* kPb = (const char*)(kP + bho);
    const char* vPb = (const char*)(vP + bho);

    float lsum = 0.f;
    f32x4 acc0 = {0.f, 0.f, 0.f, 0.f}, acc1 = {0.f, 0.f, 0.f, 0.f};
    const f32x4 zeroc = {0.f, 0.f, 0.f, 0.f};
    const int jt0 = sp * JTPS;

    auto stage = [&](int buf, int jt) {
        const char* src = (tid < 256 ? kPb : vPb) + (size_t)jt * 4096 + (tid & 255) * 16;
        char* dst = lds + buf * 8192 + (tid < 256 ? 0 : 4096) + (w & 3) * 1024;
        __builtin_amdgcn_global_load_lds((gp_t)src, (lp_t)dst, 16, 0, 0);
    };

    stage(0, jt0);
    __syncthreads();

    for (int t = 0; t < JTPS; ++t) {
        const int buf = t & 1;
        if (t + 1 < JTPS) stage(buf ^ 1, jt0 + t + 1);
        const char* kb = lds + buf * 8192;
        const char* vb = kb + 4096;

        // swapped QK^T: lane holds P[i=i0+m][j = t2*16 + g*4 + r] (log2 domain)
        f32x4 st[4];
#pragma unroll
        for (int t2 = 0; t2 < 4; ++t2) {
            const s16x8 kf = *(const s16x8*)(kb + g * 1024 + (t2 * 16 + m) * 16);
            st[t2] = __builtin_amdgcn_mfma_f32_16x16x32_bf16(kf, qf, zeroc, 0, 0, 0);
        }

        float p[16];
        float ts0 = 0.f, ts1 = 0.f, ts2 = 0.f, ts3 = 0.f;
#pragma unroll
        for (int t2 = 0; t2 < 4; ++t2) {
            const float e0 = exp2_hw(st[t2][0]);
            const float e1 = exp2_hw(st[t2][1]);
            const float e2 = exp2_hw(st[t2][2]);
            const float e3 = exp2_hw(st[t2][3]);
            p[t2 * 4 + 0] = e0; p[t2 * 4 + 1] = e1;
            p[t2 * 4 + 2] = e2; p[t2 * 4 + 3] = e3;
            ts0 += e0; ts1 += e1; ts2 += e2; ts3 += e3;
        }
        lsum += (ts0 + ts1) + (ts2 + ts3);

        union { unsigned u[4]; s16x8 v; } a0u, a1u;
#pragma unroll
        for (int e = 0; e < 4; ++e) {
            a0u.u[e] = cvt_pk_bf16(p[2 * e],     p[2 * e + 1]);
            a1u.u[e] = cvt_pk_bf16(p[8 + 2 * e], p[9 + 2 * e]);
        }

#pragma unroll
        for (int pp = 0; pp < 2; ++pp) {
            const s16x8 pa = pp ? a1u.v : a0u.v;
#pragma unroll
            for (int n0 = 0; n0 < 2; ++n0) {
                const s16x8 vf = *(const s16x8*)(vb + (pp * 128 + g * 32 + n0 * 16 + m) * 16);
                if (n0 == 0) acc0 = __builtin_amdgcn_mfma_f32_16x16x32_bf16(pa, vf, acc0, 0, 0, 0);
                else         acc1 = __builtin_amdgcn_mfma_f32_16x16x32_bf16(pa, vf, acc1, 0, 0, 0);
            }
        }
        __syncthreads();
    }

    lsum += __shfl_xor(lsum, 16);
    lsum += __shfl_xor(lsum, 32);

    const int pb = (bh * 32 + iblk) * NSP + sp;
    if (g == 0) plsum[(size_t)pb * 128 + w * 16 + m] = lsum;
    unsigned* pa = pacc2 + ((size_t)pb * 128 + w * 16) * 16;
#pragma unroll
    for (int r = 0; r < 4; ++r)
        pa[(g * 4 + r) * 16 + m] = cvt_pk_bf16(acc0[r], acc1[r]);
}

// ---- k_comb: sum split-K partials, normalize, emit rawP (proj B-fragment image) ----
__global__ __launch_bounds__(256) void k_comb(const unsigned* __restrict__ pacc2,
                                              const float* __restrict__ plsum,
                                              short* __restrict__ rawP) {
    const int b = blockIdx.x >> 6, lblk = blockIdx.x & 63;
    const int l0 = lblk * 64;
    const int t = threadIdx.x;
    const int ct2 = t >> 6, g = (t >> 4) & 3, lsub = t & 15;
    const int ii = (l0 + lsub * 4) >> 5;
    const int mm0 = (lsub * 4) & 15;
    const int hi = (lsub >> 2) & 1;

#pragma unroll
    for (int e = 0; e < 8; ++e) {
        const int row0 = (((b * 4 + ct2) * 32) + g * 8 + e) * NSP;
        float ls = 0.f, a0 = 0.f, a1 = 0.f, a2 = 0.f, a3 = 0.f;
#pragma unroll
        for (int sp = 0; sp < NSP; ++sp) {
            const unsigned* pr = pacc2 + ((size_t)(row0 + sp) * 128 + ii) * 16 + mm0;
            const uint4 u = *(const uint4*)pr;
            a0 += bfbits(u.x, hi); a1 += bfbits(u.y, hi);
            a2 += bfbits(u.z, hi); a3 += bfbits(u.w, hi);
            ls += plsum[(size_t)(row0 + sp) * 128 + ii];
        }
        const float inv = 1.0f / ls;
        short* dst = rawP + (((size_t)((b * 4 + ct2) * 4 + g) * LSEQ) + l0 + lsub * 4) * 8 + e;
        dst[0]  = f2bf(a0 * inv);
        dst[8]  = f2bf(a1 * inv);
        dst[16] = f2bf(a2 * inv);
        dst[24] = f2bf(a3 * inv);
    }
}

// ---- mfma_proj: out[b][o][l] = bias[o] + sum_c Wout[o][c] raw[c][l] ----
__global__ __launch_bounds__(256) void mfma_proj(const short* __restrict__ rawP,
                                                 const short* __restrict__ wP2,
                                                 const float* __restrict__ bias,
                                                 float* __restrict__ out) {
    const int i = blockIdx.x;
    const int slice = i & 31, ot = i >> 5;
    const int b = slice >> 4, lq = slice & 15;
    const int tid = threadIdx.x, lane = tid & 63, w = tid >> 6;
    const int m = lane & 15, g = lane >> 4;
    const int l0 = lq * 256 + w * 64;

    s16x8 wA[4];
#pragma unroll
    for (int ct = 0; ct < 4; ++ct)
        wA[ct] = *(const s16x8*)(wP2 + ((size_t)((ot * 4 + ct) * 4 + g) * 16 + m) * 8);

    f32x4 acc[4];
#pragma unroll
    for (int t = 0; t < 4; ++t) acc[t] = (f32x4){0.f, 0.f, 0.f, 0.f};

#pragma unroll
    for (int ct = 0; ct < 4; ++ct) {
        const size_t bb = (size_t)((b * 4 + ct) * 4 + g) * LSEQ;
#pragma unroll
        for (int t = 0; t < 4; ++t) {
            const s16x8 xf = *(const s16x8*)(rawP + (bb + l0 + t * 16 + m) * 8);
            acc[t] = __builtin_amdgcn_mfma_f32_16x16x32_bf16(wA[ct], xf, acc[t], 0, 0, 0);
        }
    }
    float bv[4];
#pragma unroll
    for (int r = 0; r < 4; ++r) bv[r] = bias[ot * 16 + 4 * g + r];
    float* ob = out + ((size_t)b * CIN + ot * 16) * LSEQ;
#pragma unroll
    for (int t = 0; t < 4; ++t)
#pragma unroll
        for (int r = 0; r < 4; ++r)
            ob[(size_t)(4 * g + r) * LSEQ + l0 + t * 16 + m] = acc[t][r] + bv[r];
}

extern "C" void kernel_launch(void* const* d_in, const int* in_sizes, int n_in,
                              void* d_out, int out_size, void* d_ws, size_t ws_size,
                              hipStream_t stream) {
    const float* x     = (const float*)d_in[0];
    const float* w_qkv = (const float*)d_in[1];
    const float* w_out = (const float*)d_in[2];
    const float* b_out = (const float*)d_in[3];
    float* out = (float*)d_out;
    float* ws  = (float*)d_ws;

    // ws layout (f32 units), liveness-overlaid:
    //   [0 .. 2,097,152)          qkv bf16 (uses 786,432) -> pacc2 u32 (k_attn on)
    //   [2,097,152 .. 2,621,440)  rawP bf16
    //   [2,621,440 .. 2,752,512)  plsum f32
    //   [2,752,512 .. 3,801,088)  xP bf16 -> qT (@2,752,512) + kP (@3,276,800)
    //   [3,801,088 .. 4,325,376)  vP bf16
    //   [4,325,376 .. 4,374,528)  wP bf16
    //   [4,374,528 .. 4,390,912)  wP2 bf16
    //   [4,390,912 .. 4,391,424)  ss f32 (512)
    short*    qkv    = (short*)ws;
    unsigned* pacc2  = (unsigned*)ws;
    short*    rawP   = (short*)(ws + 2097152);
    float*    plsum  = ws + 2621440;
    short*    xP     = (short*)(ws + 2752512);
    short*    qT     = (short*)(ws + 2752512);
    short*    kP     = (short*)(ws + 3276800);
    short*    vP     = (short*)(ws + 3801088);
    short*    wP     = (short*)(ws + 4325376);
    short*    wP2    = (short*)(ws + 4374528);
    float*    ss     = ws + 4390912;

    pack_xw  <<<1088, 256, 0, stream>>>(x, w_qkv, w_out, xP, wP, wP2, ss);
    mfma_qkv <<<768,  256, 0, stream>>>(xP, wP, qkv, ss);
    k_pack   <<<512,  256, 0, stream>>>(qkv, ss, qT, kP, vP);
    k_attn   <<<1024, 512, 0, stream>>>(qT, kP, vP, pacc2, plsum);
    k_comb   <<<128,  256, 0, stream>>>(pacc2, plsum, rawP);
    mfma_proj<<<512,  256, 0, stream>>>(rawP, wP2, b_out, out);
}

// Round 13
// 67.048 us; speedup vs baseline: 1.0139x; 1.0139x over previous
//
#include <hip/hip_runtime.h>
#include <math.h>

#define LSEQ 4096
#define CIN  256
#define HID  128
#define O3   384
#define NSP  4
#define JTPS (64 / NSP)   // j-tiles per split

typedef float f32x4 __attribute__((ext_vector_type(4)));
typedef short s16x8 __attribute__((ext_vector_type(8)));

typedef const __attribute__((address_space(1))) char* gp_t;
typedef __attribute__((address_space(3))) char* lp_t;

__device__ __forceinline__ short f2bf(float f) {
    union { float f; unsigned u; } c; c.f = f;
    unsigned r = (c.u + 0x7FFFu + ((c.u >> 16) & 1u)) >> 16;
    return (short)r;
}

__device__ __forceinline__ float bf2f(short s) {
    union { unsigned u; float f; } c;
    c.u = ((unsigned)(unsigned short)s) << 16;
    return c.f;
}

__device__ __forceinline__ unsigned cvt_pk_bf16(float lo, float hi) {
    unsigned r;
    asm("v_cvt_pk_bf16_f32 %0, %1, %2" : "=v"(r) : "v"(lo), "v"(hi));
    return r;
}

__device__ __forceinline__ float exp2_hw(float x) {
    float r;
    asm("v_exp_f32 %0, %1" : "=v"(r) : "v"(x));
    return r;
}

__device__ __forceinline__ float bfbits(unsigned v, int hi) {
    union { unsigned u; float f; } c;
    c.u = hi ? (v & 0xffff0000u) : (v << 16);
    return c.f;
}

// ---- pack_xw: x -> xP (B-fragment image), w_qkv -> wP, w_out -> wP2; zero ss ----
__global__ __launch_bounds__(256) void pack_xw(const float* __restrict__ x,
                                               const float* __restrict__ wq,
                                               const float* __restrict__ wo,
                                               short* __restrict__ xP,
                                               short* __restrict__ wP,
                                               short* __restrict__ wP2,
                                               float* __restrict__ ss) {
    const int tid = threadIdx.x;
    if (blockIdx.x >= 1024) {
        if (blockIdx.x == 1024) { ss[tid] = 0.f; ss[256 + tid] = 0.f; }
        const int gid = (blockIdx.x - 1024) * 256 + tid;
        s16x8 o;
        if (gid < 12288) {
            const int m = gid & 15, g = (gid >> 4) & 3, ct = (gid >> 6) & 7;
            const int ot = gid >> 9;
            const float* src = wq + (ot * 16 + m) * 256 + ct * 32 + g * 8;
#pragma unroll
            for (int e = 0; e < 8; ++e) o[e] = f2bf(src[e]);
            *(s16x8*)(wP + (size_t)gid * 8) = o;
        } else {
            const int g2 = gid - 12288;  // 0..4095
            const int m = g2 & 15, g = (g2 >> 4) & 3, ct = (g2 >> 6) & 3;
            const int ot = g2 >> 8;
            const float* src = wo + (ot * 16 + m) * 128 + ct * 32 + g * 8;
#pragma unroll
            for (int e = 0; e < 8; ++e) o[e] = f2bf(src[e]);
            *(s16x8*)(wP2 + (size_t)g2 * 8) = o;
        }
        return;
    }
    __shared__ float tile[32][68];
    const int b = blockIdx.x >> 9, ct = (blockIdx.x >> 6) & 7, lt = blockIdx.x & 63;
    const int c = tid >> 3, l8 = (tid & 7) * 8;
    const float* xb = x + ((size_t)b * CIN + ct * 32 + c) * LSEQ + lt * 64 + l8;
    *(float4*)&tile[c][l8]     = *(const float4*)xb;
    *(float4*)&tile[c][l8 + 4] = *(const float4*)(xb + 4);
    __syncthreads();
    const int g = tid >> 6, l = tid & 63;
    s16x8 o;
#pragma unroll
    for (int e = 0; e < 8; ++e) o[e] = f2bf(tile[g * 8 + e][l]);
    *(s16x8*)(xP + ((size_t)((b * 8 + ct) * 4 + g) * LSEQ + lt * 64 + l) * 8) = o;
}

// ---- mfma_qkv: qkv(bf16)[b][o][l] = sum_c W[o][c] X[c][l]; fused row sum-of-squares ----
__global__ __launch_bounds__(256) void mfma_qkv(const short* __restrict__ xP,
                                                const short* __restrict__ wP,
                                                short* __restrict__ qkv,
                                                float* __restrict__ ss) {
    const int i = blockIdx.x;
    const int slice = i & 31, ot = i >> 5;
    const int b = slice >> 4, lq = slice & 15;
    const int tid = threadIdx.x, lane = tid & 63, w = tid >> 6;
    const int m = lane & 15, g = lane >> 4;
    const int l0 = lq * 256 + w * 64;

    s16x8 wA[8];
#pragma unroll
    for (int ct = 0; ct < 8; ++ct)
        wA[ct] = *(const s16x8*)(wP + ((size_t)((ot * 8 + ct) * 4 + g) * 16 + m) * 8);

    f32x4 acc[4];
#pragma unroll
    for (int t = 0; t < 4; ++t) acc[t] = (f32x4){0.f, 0.f, 0.f, 0.f};

#pragma unroll
    for (int ct = 0; ct < 8; ++ct) {
        const size_t bb = (size_t)((b * 8 + ct) * 4 + g) * LSEQ;
#pragma unroll
        for (int t = 0; t < 4; ++t) {
            const s16x8 xf = *(const s16x8*)(xP + (bb + l0 + t * 16 + m) * 8);
            acc[t] = __builtin_amdgcn_mfma_f32_16x16x32_bf16(wA[ct], xf, acc[t], 0, 0, 0);
        }
    }
    short* qb = qkv + ((size_t)b * O3 + ot * 16) * LSEQ;
#pragma unroll
    for (int t = 0; t < 4; ++t)
#pragma unroll
        for (int r = 0; r < 4; ++r)
            qb[(size_t)(4 * g + r) * LSEQ + l0 + t * 16 + m] = f2bf(acc[t][r]);

    if (ot < 16) {  // q,k rows need the norm
        float s4[4];
#pragma unroll
        for (int r = 0; r < 4; ++r) {
            float s = acc[0][r] * acc[0][r];
#pragma unroll
            for (int t = 1; t < 4; ++t) s = fmaf(acc[t][r], acc[t][r], s);
#pragma unroll
            for (int mk = 1; mk < 16; mk <<= 1) s += __shfl_xor(s, mk);
            s4[r] = s;
        }
        if (m == 0) {
#pragma unroll
            for (int r = 0; r < 4; ++r)
                atomicAdd(ss + b * 256 + ot * 16 + 4 * g + r, s4[r]);
        }
    }
}

// ---- k_pack: qkv bf16 -> qT/kP/vP (scales from ss applied to q,k) ----
// vP fragment-image: group idx t=(pp*4+g)*32+dd -> {V[dd][pp*32+(e>>2)*16+g*4+(e&3)]}
__global__ __launch_bounds__(256) void k_pack(const short* __restrict__ qkv,
                                              const float* __restrict__ ss,
                                              short* __restrict__ qT,
                                              short* __restrict__ kP,
                                              short* __restrict__ vP) {
    __shared__ float tile[32][68];
    const int tid = threadIdx.x;
    const int bh = blockIdx.x & 7, ch = blockIdx.x >> 3;
    const int b = bh >> 2, h = bh & 3;
    const int l0 = ch * 64;
    const short* qg = qkv + ((size_t)b * O3 + h * 32) * LSEQ;
    const short* kg = qg + (size_t)HID * LSEQ;
    const short* vg = qg + (size_t)2 * HID * LSEQ;
    const size_t bho = (size_t)bh * (LSEQ * 32);
    const int d = tid >> 3, c8 = (tid & 7) * 8;

    // ---- Q: transpose + scale -> qT[i][d] ----
    {
        const s16x8 qv = *(const s16x8*)(qg + (size_t)d * LSEQ + l0 + c8);
#pragma unroll
        for (int e = 0; e < 8; ++e) tile[d][c8 + e] = bf2f(qv[e]);
    }
    __syncthreads();
    {
        const int i = tid >> 2, dseg = (tid & 3) * 8;
        s16x8 o;
#pragma unroll
        for (int e = 0; e < 8; ++e) {
            const float sc = 14.4269504088896340736f /
                             fmaxf(sqrtf(ss[b * 256 + h * 32 + dseg + e]), 1e-12f);
            o[e] = f2bf(tile[dseg + e][i] * sc);
        }
        *(s16x8*)(qT + bho + (size_t)(l0 + i) * 32 + dseg) = o;
    }
    __syncthreads();
    // ---- K ----
    {
        const s16x8 kv = *(const s16x8*)(kg + (size_t)d * LSEQ + l0 + c8);
#pragma unroll
        for (int e = 0; e < 8; ++e) tile[d][c8 + e] = bf2f(kv[e]);
    }
    __syncthreads();
    {
        const int gg = tid >> 6, jl = tid & 63;
        s16x8 o;
#pragma unroll
        for (int e = 0; e < 8; ++e) {
            const float sc = 1.0f /
                             fmaxf(sqrtf(ss[b * 256 + 128 + h * 32 + gg * 8 + e]), 1e-12f);
            o[e] = f2bf(tile[gg * 8 + e][jl] * sc);
        }
        *(s16x8*)(kP + bho + (size_t)ch * 2048 + gg * 512 + jl * 8) = o;
    }
    __syncthreads();
    // ---- V (unscaled), PV-fragment image ----
    {
        const s16x8 vv = *(const s16x8*)(vg + (size_t)d * LSEQ + l0 + c8);
#pragma unroll
        for (int e = 0; e < 8; ++e) tile[d][c8 + e] = bf2f(vv[e]);
    }
    __syncthreads();
    {
        const int pp = tid >> 7, g = (tid >> 5) & 3, dd = tid & 31;
        s16x8 o;
#pragma unroll
        for (int e = 0; e < 8; ++e)
            o[e] = f2bf(tile[dd][pp * 32 + ((e >> 2) * 16) + g * 4 + (e & 3)]);
        *(s16x8*)(vP + bho + (size_t)ch * 2048 + tid * 8) = o;
    }
}

// ---- k_attn: MFMA flash attention, split-K=4, exp2 softmax, bf16 partials ----
__global__ __launch_bounds__(512, 8) void k_attn(const short* __restrict__ qT,
                                                 const short* __restrict__ kP,
                                                 const short* __restrict__ vP,
                                                 unsigned* __restrict__ pacc2,
                                                 float* __restrict__ plsum) {
    __shared__ float4 lds_v[1024];   // 16 KB: 2 buffers x (K 4KB | V 4KB)
    char* lds = (char*)lds_v;
    const int tid = threadIdx.x;
    const int lane = tid & 63, w = tid >> 6;
    const int m = lane & 15, g = lane >> 4;
    const int bh = blockIdx.x & 7;           // XCD-friendly
    const int rest = blockIdx.x >> 3;        // 0..127
    const int iblk = rest & 31, sp = rest >> 5;
    const size_t bho = (size_t)bh * (LSEQ * 32);
    const int i0 = iblk * 128 + w * 16;

    const s16x8 qf = *(const s16x8*)(qT + bho + (size_t)(i0 + m) * 32 + g * 8);
    const char* kPb = (const char*)(kP + bho);
    const char* vPb = (const char*)(vP + bho);

    float lsum = 0.f;
    f32x4 acc0 = {0.f, 0.f, 0.f, 0.f}, acc1 = {0.f, 0.f, 0.f, 0.f};
    const f32x4 zeroc = {0.f, 0.f, 0.f, 0.f};
    const int jt0 = sp * JTPS;

    auto stage = [&](int buf, int jt) {
        const char* src = (tid < 256 ? kPb : vPb) + (size_t)jt * 4096 + (tid & 255) * 16;
        char* dst = lds + buf * 8192 + (tid < 256 ? 0 : 4096) + (w & 3) * 1024;
        __builtin_amdgcn_global_load_lds((gp_t)src, (lp_t)dst, 16, 0, 0);
    };

    stage(0, jt0);
    __syncthreads();

    for (int t = 0; t < JTPS; ++t) {
        const int buf = t & 1;
        if (t + 1 < JTPS) stage(buf ^ 1, jt0 + t + 1);
        const char* kb = lds + buf * 8192;
        const char* vb = kb + 4096;

        // swapped QK^T: lane holds P[i=i0+m][j = t2*16 + g*4 + r] (log2 domain)
        f32x4 st[4];
#pragma unroll
        for (int t2 = 0; t2 < 4; ++t2) {
            const s16x8 kf = *(const s16x8*)(kb + g * 1024 + (t2 * 16 + m) * 16);
            st[t2] = __builtin_amdgcn_mfma_f32_16x16x32_bf16(kf, qf, zeroc, 0, 0, 0);
        }

        float p[16];
        float ts0 = 0.f, ts1 = 0.f, ts2 = 0.f, ts3 = 0.f;
#pragma unroll
        for (int t2 = 0; t2 < 4; ++t2) {
            const float e0 = exp2_hw(st[t2][0]);
            const float e1 = exp2_hw(st[t2][1]);
            const float e2 = exp2_hw(st[t2][2]);
            const float e3 = exp2_hw(st[t2][3]);
            p[t2 * 4 + 0] = e0; p[t2 * 4 + 1] = e1;
            p[t2 * 4 + 2] = e2; p[t2 * 4 + 3] = e3;
            ts0 += e0; ts1 += e1; ts2 += e2; ts3 += e3;
        }
        lsum += (ts0 + ts1) + (ts2 + ts3);

        union { unsigned u[4]; s16x8 v; } a0u, a1u;
#pragma unroll
        for (int e = 0; e < 4; ++e) {
            a0u.u[e] = cvt_pk_bf16(p[2 * e],     p[2 * e + 1]);
            a1u.u[e] = cvt_pk_bf16(p[8 + 2 * e], p[9 + 2 * e]);
        }

#pragma unroll
        for (int pp = 0; pp < 2; ++pp) {
            const s16x8 pa = pp ? a1u.v : a0u.v;
#pragma unroll
            for (int n0 = 0; n0 < 2; ++n0) {
                const s16x8 vf = *(const s16x8*)(vb + (pp * 128 + g * 32 + n0 * 16 + m) * 16);
                if (n0 == 0) acc0 = __builtin_amdgcn_mfma_f32_16x16x32_bf16(pa, vf, acc0, 0, 0, 0);
                else         acc1 = __builtin_amdgcn_mfma_f32_16x16x32_bf16(pa, vf, acc1, 0, 0, 0);
            }
        }
        __syncthreads();
    }

    lsum += __shfl_xor(lsum, 16);
    lsum += __shfl_xor(lsum, 32);

    const int pb = (bh * 32 + iblk) * NSP + sp;
    if (g == 0) plsum[(size_t)pb * 128 + w * 16 + m] = lsum;
    unsigned* pa = pacc2 + ((size_t)pb * 128 + w * 16) * 16;
#pragma unroll
    for (int r = 0; r < 4; ++r)
        pa[(g * 4 + r) * 16 + m] = cvt_pk_bf16(acc0[r], acc1[r]);
}

// ---- k_comb: sum split-K partials, normalize, emit rawP (proj B-fragment image) ----
__global__ __launch_bounds__(256) void k_comb(const unsigned* __restrict__ pacc2,
                                              const float* __restrict__ plsum,
                                              short* __restrict__ rawP) {
    const int b = blockIdx.x >> 6, lblk = blockIdx.x & 63;
    const int l0 = lblk * 64;
    const int t = threadIdx.x;
    const int ct2 = t >> 6, g = (t >> 4) & 3, lsub = t & 15;
    const int ii = (l0 + lsub * 4) >> 5;
    const int mm0 = (lsub * 4) & 15;
    const int hi = (lsub >> 2) & 1;

#pragma unroll
    for (int e = 0; e < 8; ++e) {
        const int row0 = (((b * 4 + ct2) * 32) + g * 8 + e) * NSP;
        float ls = 0.f, a0 = 0.f, a1 = 0.f, a2 = 0.f, a3 = 0.f;
#pragma unroll
        for (int sp = 0; sp < NSP; ++sp) {
            const unsigned* pr = pacc2 + ((size_t)(row0 + sp) * 128 + ii) * 16 + mm0;
            const uint4 u = *(const uint4*)pr;
            a0 += bfbits(u.x, hi); a1 += bfbits(u.y, hi);
            a2 += bfbits(u.z, hi); a3 += bfbits(u.w, hi);
            ls += plsum[(size_t)(row0 + sp) * 128 + ii];
        }
        const float inv = 1.0f / ls;
        short* dst = rawP + (((size_t)((b * 4 + ct2) * 4 + g) * LSEQ) + l0 + lsub * 4) * 8 + e;
        dst[0]  = f2bf(a0 * inv);
        dst[8]  = f2bf(a1 * inv);
        dst[16] = f2bf(a2 * inv);
        dst[24] = f2bf(a3 * inv);
    }
}

// ---- mfma_proj: out[b][o][l] = bias[o] + sum_c Wout[o][c] raw[c][l] ----
__global__ __launch_bounds__(256) void mfma_proj(const short* __restrict__ rawP,
                                                 const short* __restrict__ wP2,
                                                 const float* __restrict__ bias,
                                                 float* __restrict__ out) {
    const int i = blockIdx.x;
    const int slice = i & 31, ot = i >> 5;
    const int b = slice >> 4, lq = slice & 15;
    const int tid = threadIdx.x, lane = tid & 63, w = tid >> 6;
    const int m = lane & 15, g = lane >> 4;
    const int l0 = lq * 256 + w * 64;

    s16x8 wA[4];
#pragma unroll
    for (int ct = 0; ct < 4; ++ct)
        wA[ct] = *(const s16x8*)(wP2 + ((size_t)((ot * 4 + ct) * 4 + g) * 16 + m) * 8);

    f32x4 acc[4];
#pragma unroll
    for (int t = 0; t < 4; ++t) acc[t] = (f32x4){0.f, 0.f, 0.f, 0.f};

#pragma unroll
    for (int ct = 0; ct < 4; ++ct) {
        const size_t bb = (size_t)((b * 4 + ct) * 4 + g) * LSEQ;
#pragma unroll
        for (int t = 0; t < 4; ++t) {
            const s16x8 xf = *(const s16x8*)(rawP + (bb + l0 + t * 16 + m) * 8);
            acc[t] = __builtin_amdgcn_mfma_f32_16x16x32_bf16(wA[ct], xf, acc[t], 0, 0, 0);
        }
    }
    float bv[4];
#pragma unroll
    for (int r = 0; r < 4; ++r) bv[r] = bias[ot * 16 + 4 * g + r];
    float* ob = out + ((size_t)b * CIN + ot * 16) * LSEQ;
#pragma unroll
    for (int t = 0; t < 4; ++t)
#pragma unroll
        for (int r = 0; r < 4; ++r)
            ob[(size_t)(4 * g + r) * LSEQ + l0 + t * 16 + m] = acc[t][r] + bv[r];
}

extern "C" void kernel_launch(void* const* d_in, const int* in_sizes, int n_in,
                              void* d_out, int out_size, void* d_ws, size_t ws_size,
                              hipStream_t stream) {
    const float* x     = (const float*)d_in[0];
    const float* w_qkv = (const float*)d_in[1];
    const float* w_out = (const float*)d_in[2];
    const float* b_out = (const float*)d_in[3];
    float* out = (float*)d_out;
    float* ws  = (float*)d_ws;

    // ws layout (f32 units), liveness-overlaid:
    //   [0 .. 2,097,152)          qkv bf16 (uses 786,432) -> pacc2 u32 (k_attn on)
    //   [2,097,152 .. 2,621,440)  rawP bf16
    //   [2,621,440 .. 2,752,512)  plsum f32
    //   [2,752,512 .. 3,801,088)  xP bf16 -> qT (@2,752,512) + kP (@3,276,800)
    //   [3,801,088 .. 4,325,376)  vP bf16
    //   [4,325,376 .. 4,374,528)  wP bf16
    //   [4,374,528 .. 4,390,912)  wP2 bf16
    //   [4,390,912 .. 4,391,424)  ss f32 (512)
    short*    qkv    = (short*)ws;
    unsigned* pacc2  = (unsigned*)ws;
    short*    rawP   = (short*)(ws + 2097152);
    float*    plsum  = ws + 2621440;
    short*    xP     = (short*)(ws + 2752512);
    short*    qT     = (short*)(ws + 2752512);
    short*    kP     = (short*)(ws + 3276800);
    short*    vP     = (short*)(ws + 3801088);
    short*    wP     = (short*)(ws + 4325376);
    short*    wP2    = (short*)(ws + 4374528);
    float*    ss     = ws + 4390912;

    pack_xw  <<<1088, 256, 0, stream>>>(x, w_qkv, w_out, xP, wP, wP2, ss);
    mfma_qkv <<<768,  256, 0, stream>>>(xP, wP, qkv, ss);
    k_pack   <<<512,  256, 0, stream>>>(qkv, ss, qT, kP, vP);
    k_attn   <<<1024, 512, 0, stream>>>(qT, kP, vP, pacc2, plsum);
    k_comb   <<<128,  256, 0, stream>>>(pacc2, plsum, rawP);
    mfma_proj<<<512,  256, 0, stream>>>(rawP, wP2, b_out, out);
}